// Round 19
// baseline (753.089 us; speedup 1.0000x reference)
//
#include <hip/hip_runtime.h>
#include <hip/hip_bf16.h>
#include <float.h>
#include <math.h>

#define NQ    64
#define DF    256
#define CC    345
#define KSF   8      // 256/32
#define KSC   11     // ceil(345/32)
#define NBM   768    // main dist blocks
#define FRESH (1 << 30)
#define EPSN  1e-12f

typedef __attribute__((ext_vector_type(8))) short short8;
typedef __attribute__((ext_vector_type(4))) float f32x4;

// ---- global->LDS DMA (size is a literal) ---------------------------------
__device__ __forceinline__ void gld16(const void* g, void* l) {
  __builtin_amdgcn_global_load_lds(
      static_cast<const uint32_t*>(g), static_cast<uint32_t*>(l), 16, 0, 0);
}
__device__ __forceinline__ void gld4(const void* g, void* l) {
  __builtin_amdgcn_global_load_lds(
      static_cast<const uint32_t*>(g), static_cast<uint32_t*>(l), 4, 0, 0);
}

// ---- counted waitcnt helpers (literal N; sched fence per rule #18) -------
__device__ __forceinline__ void wait_vm0() {
  asm volatile("s_waitcnt vmcnt(0)" ::: "memory");
  __builtin_amdgcn_sched_barrier(0);
}
__device__ __forceinline__ void wait_vm4() {
  asm volatile("s_waitcnt vmcnt(4)" ::: "memory");
  __builtin_amdgcn_sched_barrier(0);
}
__device__ __forceinline__ void wait_vm8() {
  asm volatile("s_waitcnt vmcnt(8)" ::: "memory");
  __builtin_amdgcn_sched_barrier(0);
}
__device__ __forceinline__ void wait_vm9() {
  asm volatile("s_waitcnt vmcnt(9)" ::: "memory");
  __builtin_amdgcn_sched_barrier(0);
}
__device__ __forceinline__ void wait_lgkm0() {
  asm volatile("s_waitcnt lgkmcnt(0)" ::: "memory");
  __builtin_amdgcn_sched_barrier(0);
}
__device__ __forceinline__ void raw_barrier() {
  __builtin_amdgcn_sched_barrier(0);
  __builtin_amdgcn_s_barrier();
  __builtin_amdgcn_sched_barrier(0);
}

// ---------------- zero d_out ----------------------------------------------
__global__ void zero_out(float* out) {
  if (threadIdx.x < 2) out[threadIdx.x] = 0.f;
}

// ---------------- block-wide reductions -----------------------------------
__device__ __forceinline__ float blockReduceSum(float v, float* sbuf) {
  __syncthreads();
  #pragma unroll
  for (int o = 32; o > 0; o >>= 1) v += __shfl_down(v, o);
  int w = threadIdx.x >> 6;
  if ((threadIdx.x & 63) == 0) sbuf[w] = v;
  __syncthreads();
  if (threadIdx.x == 0) {
    float s = 0.f;
    int nw = blockDim.x >> 6;
    for (int i = 0; i < nw; ++i) s += sbuf[i];
    sbuf[0] = s;
  }
  __syncthreads();
  return sbuf[0];
}

__device__ __forceinline__ float blockReduceMax(float v, float* sbuf) {
  __syncthreads();
  #pragma unroll
  for (int o = 32; o > 0; o >>= 1) v = fmaxf(v, __shfl_down(v, o));
  int w = threadIdx.x >> 6;
  if ((threadIdx.x & 63) == 0) sbuf[w] = v;
  __syncthreads();
  if (threadIdx.x == 0) {
    float s = -FLT_MAX;
    int nw = blockDim.x >> 6;
    for (int i = 0; i < nw; ++i) s = fmaxf(s, sbuf[i]);
    sbuf[0] = s;
  }
  __syncthreads();
  return sbuf[0];
}

// ------------- top-k insert, list sorted (value desc, index asc) ----------
template<int T>
__device__ __forceinline__ void topk_insert(float v, int id, float (&lv)[T], int (&li)[T]) {
  if (!((v > lv[T-1]) || (v == lv[T-1] && id < li[T-1]))) return;
  #pragma unroll
  for (int p = T-1; p > 0; --p) {
    bool up = (v > lv[p-1]) || (v == lv[p-1] && id < li[p-1]);
    if (up) { lv[p] = lv[p-1]; li[p] = li[p-1]; }
    else    { lv[p] = v; li[p] = id; return; }
  }
  lv[0] = v; li[0] = id;
}

template<int T>
__device__ __forceinline__ void merge4(const float* sv, const int* si, int t,
                                       float* dv, int* di) {
  float fv[T]; int fi[T];
  #pragma unroll
  for (int i = 0; i < T; ++i) { fv[i] = -FLT_MAX; fi[i] = 0x7fffffff; }
  for (int s = 0; s < 4; ++s)
    #pragma unroll
    for (int i = 0; i < T; ++i)
      topk_insert<T>(sv[(t*4+s)*T+i], si[(t*4+s)*T+i], fv, fi);
  #pragma unroll
  for (int i = 0; i < T; ++i) { dv[t*T+i] = fv[i]; di[t*T+i] = fi[i]; }
}

// ---------------- rowmap fill ---------------------------------------------
__global__ void fill_rowmap(int* rowmap, int n) {
  int i = blockIdx.x * blockDim.x + threadIdx.x;
  if (i < n) rowmap[i] = -1;
}

// -------- prep: softmax, normalize queries -> MFMA frag pack, updates -----
__global__ __launch_bounds__(384) void prep_kernel(
    const float* __restrict__ tf, const float* __restrict__ fc1,
    const float* __restrict__ fc2, const int* __restrict__ idx,
    const float* __restrict__ featm, const float* __restrict__ fc1m,
    const float* __restrict__ fc2m,
    short* __restrict__ Qp_feat, short* __restrict__ Qp_fc1, short* __restrict__ Qp_fc2,
    float* __restrict__ featU, float* __restrict__ fc1U, float* __restrict__ fc2U,
    int* __restrict__ rowmap)
{
  __shared__ float sbuf[8];
  const int b = blockIdx.x, t = threadIdx.x;
  const int trow = idx[b];
  const int qt = b >> 4, qr = b & 15;

  {
    float x = (t < DF) ? tf[b*DF + t] : 0.f;
    float ss = blockReduceSum(x*x, sbuf);
    float inv = 1.f / fmaxf(sqrtf(ss), EPSN);
    if (t < DF) {
      featU[b*DF + t] = 0.9f * featm[(size_t)trow*DF + t] + 0.1f * x;
      int ks = t >> 5, lg = (t >> 3) & 3, j = t & 7;
      int lane = qr + lg*16;
      union { __hip_bfloat16 h; short s; } cv;
      cv.h = __float2bfloat16(x * inv);
      Qp_feat[((qt*KSF + ks)*64 + lane)*8 + j] = cv.s;
    }
  }
  {
    float y = (t < CC) ? fc1[b*CC + t] : -FLT_MAX;
    float mx = blockReduceMax(y, sbuf);
    float e = (t < CC) ? expf(y - mx) : 0.f;
    float se = blockReduceSum(e, sbuf);
    float s = e / se;
    float s2 = blockReduceSum(s*s, sbuf);
    float inv2 = 1.f / fmaxf(sqrtf(s2), EPSN);
    if (t < CC) fc1U[b*CC + t] = 0.9f * fc1m[(size_t)trow*CC + t] + 0.1f * s;
    if (t < KSC*32) {
      int ks = t >> 5, lg = (t >> 3) & 3, j = t & 7;
      int lane = qr + lg*16;
      union { __hip_bfloat16 h; short s; } cv;
      cv.h = __float2bfloat16((t < CC) ? s * inv2 : 0.f);
      Qp_fc1[((qt*KSC + ks)*64 + lane)*8 + j] = cv.s;
    }
  }
  {
    float y = (t < CC) ? fc2[b*CC + t] : -FLT_MAX;
    float mx = blockReduceMax(y, sbuf);
    float e = (t < CC) ? expf(y - mx) : 0.f;
    float se = blockReduceSum(e, sbuf);
    float s = e / se;
    float s2 = blockReduceSum(s*s, sbuf);
    float inv2 = 1.f / fmaxf(sqrtf(s2), EPSN);
    if (t < CC) fc2U[b*CC + t] = 0.9f * fc2m[(size_t)trow*CC + t] + 0.1f * s;
    if (t < KSC*32) {
      int ks = t >> 5, lg = (t >> 3) & 3, j = t & 7;
      int lane = qr + lg*16;
      union { __hip_bfloat16 h; short s; } cv;
      cv.h = __float2bfloat16((t < CC) ? s * inv2 : 0.f);
      Qp_fc2[((qt*KSC + ks)*64 + lane)*8 + j] = cv.s;
    }
  }
  if (t == 0) rowmap[trow] = b;
}

// -------- dist (r14 verbatim): DMA staging + swapped MFMA, register topk --
template<int D, int KS, int T>
__global__ __launch_bounds__(256, 3) void dist_topk11(
    const float* __restrict__ bank, const float* __restrict__ ubank,
    const int* __restrict__ uids, const short8* __restrict__ Qp,
    float* __restrict__ cand_v, int* __restrict__ cand_i,
    int nmain, int ntq, int ntr)
{
  constexpr bool FEAT = (D == 256);
  constexpr int GROW = D * 4;                  // global row bytes: 1024/1380
  constexpr int SROW = FEAT ? 1024 : 1392;     // LDS row stride (16B mult)
  constexpr int BUFB = 16 * SROW;

  __shared__ __align__(16) char smem[2*BUFB + 128];
  char* k344 = smem + 2*BUFB;                  // [2][16] f32 (fc k=344)

  const int t = threadIdx.x, l = t & 63, w = t >> 6;
  const int lc = l & 15, lg = l >> 4;
  const bool corr = ((int)blockIdx.x >= nmain);
  const float* srcb = corr ? ubank : bank;

  int tile0, nt;
  if (corr) { tile0 = blockIdx.x - nmain; nt = 1; }
  else {
    int b = blockIdx.x;
    tile0 = b*ntq + (b < ntr ? b : ntr);
    nt = ntq + (b < ntr ? 1 : 0);
  }

  short8 afr[KS];                              // wave w's 16 queries (B-op)
  #pragma unroll
  for (int ks = 0; ks < KS; ++ks) afr[ks] = Qp[(w*KS + ks)*64 + l];

  auto STAGE = [&](int tile, int pn) {
    const char* tb = (const char*)srcb + (size_t)tile * (size_t)(16*GROW);
    char* bb = smem + pn*BUFB;
    #pragma unroll
    for (int r2 = 0; r2 < 4; ++r2) {
      int row = w*4 + r2;                      // wave-uniform
      if (FEAT) {
        // pre-swizzled source so swizzled reads see linear data (rule #21)
        gld16(tb + row*1024 + ((l ^ (row & 7)) * 16), bb + row*1024);
      } else {
        gld16(tb + row*1380 + l*16, bb + row*1392);
        if (l < 22) gld16(tb + row*1380 + 1024 + l*16, bb + row*1392 + 1024);
      }
    }
    if (!FEAT && w == 0 && l < 16)
      gld4(tb + l*1380 + 1376, k344 + pn*64);
  };

  STAGE(tile0, 0);
  if (nt > 1) STAGE(tile0 + 1, 1);

  float lv[T]; int li[T];
  #pragma unroll
  for (int i = 0; i < T; ++i) { lv[i] = -FLT_MAX; li[i] = 0x7fffffff; }

  for (int it = 0; it < nt; ++it) {
    const int pn = it & 1;

    // wait: tile it's stage complete; tile it+1 stays in flight
    if (it + 1 < nt) {
      if (FEAT) wait_vm4();
      else if (w == 0) wait_vm9();
      else wait_vm8();
    } else {
      wait_vm0();
    }
    raw_barrier();                             // all waves' portions landed

    const char* bb = smem + pn*BUFB;
    f32x4 acc = (f32x4){0.f, 0.f, 0.f, 0.f};
    float sq = 0.f;

    #pragma unroll
    for (int ks = 0; ks < KS; ++ks) {
      float v[8];
      if (!FEAT && ks == KS-1 && lg == 3) {    // fc tail: only k=344 valid
        v[0] = *(const float*)(k344 + pn*64 + lc*4);
        #pragma unroll
        for (int j = 1; j < 8; ++j) v[j] = 0.f;
      } else if (FEAT) {
        int g0 = ks*8 + lg*2;
        float4 a = *(const float4*)(bb + lc*1024 + ((g0 ^ (lc & 7)) * 16));
        float4 c = *(const float4*)(bb + lc*1024 + (((g0 + 1) ^ (lc & 7)) * 16));
        v[0]=a.x; v[1]=a.y; v[2]=a.z; v[3]=a.w;
        v[4]=c.x; v[5]=c.y; v[6]=c.z; v[7]=c.w;
      } else {
        const char* p = bb + lc*1392 + ks*128 + lg*32;
        float4 a = *(const float4*)p;
        float4 c = *(const float4*)(p + 16);
        v[0]=a.x; v[1]=a.y; v[2]=a.z; v[3]=a.w;
        v[4]=c.x; v[5]=c.y; v[6]=c.z; v[7]=c.w;
      }
      #pragma unroll
      for (int j = 0; j < 8; ++j) sq += v[j]*v[j];
      union { short8 s8; __hip_bfloat162 h2[4]; } fb;
      #pragma unroll
      for (int j = 0; j < 4; ++j)
        fb.h2[j] = __float22bfloat162_rn(make_float2(v[2*j], v[2*j+1]));
      // SWAPPED: rows as A, queries as B -> D[row][query]
      acc = __builtin_amdgcn_mfma_f32_16x16x32_bf16(fb.s8, afr[ks], acc, 0, 0, 0);
    }

    // row norms: lane holds row lc's partial; xor-reduce; redistribute
    float s = sq;
    s += __shfl_xor(s, 16);
    s += __shfl_xor(s, 32);
    float ri_own = 1.f / fmaxf(sqrtf(s), EPSN);   // norm of row lc
    float ri[4];
    #pragma unroll
    for (int j = 0; j < 4; ++j) ri[j] = __shfl(ri_own, lg*4 + j);

    wait_lgkm0();                              // all LDS reads of buf pn done
    raw_barrier();
    if (it + 2 < nt) STAGE(tile0 + it + 2, pn);  // refill freed buffer

    // register-only topk: lane (lc,lg) = query w*16+lc, rows lg*4+{0..3}
    if (corr) {
      #pragma unroll
      for (int j = 0; j < 4; ++j)
        topk_insert<T>(acc[j] * ri[j], uids[tile0*16 + lg*4 + j] | FRESH, lv, li);
    } else {
      const int gb = (tile0 + it) * 16 + lg*4;
      #pragma unroll
      for (int j = 0; j < 4; ++j)
        topk_insert<T>(acc[j] * ri[j], gb + j, lv, li);
    }
  }

  // write out: slot = blockIdx*4 + lg (row-partition), q = w*16 + lc
  size_t base = (((size_t)blockIdx.x*4 + lg)*64 + w*16 + lc)*T;
  #pragma unroll
  for (int i = 0; i < T; ++i) { cand_v[base + i] = lv[i]; cand_i[base + i] = li[i]; }
}

// -------- fused merge: one block per query, slots -> topout ---------------
template<int T>
__global__ __launch_bounds__(256) void merge_fused(
    const float* __restrict__ cv, const int* __restrict__ ci,
    const int* __restrict__ rowmap, int nslots,
    int* __restrict__ topout)      // stride 6
{
  __shared__ float sv[256*T]; __shared__ int si[256*T];
  __shared__ float sv2[64*T]; __shared__ int si2[64*T];
  const int q = blockIdx.x, t = threadIdx.x;
  float lv[T]; int li[T];
  #pragma unroll
  for (int i = 0; i < T; ++i) { lv[i] = -FLT_MAX; li[i] = 0x7fffffff; }
  for (int c = t; c < nslots; c += 256) {
    size_t base = ((size_t)c*64 + q)*T;
    #pragma unroll
    for (int i = 0; i < T; ++i) {
      int id = ci[base + i];
      if ((id & FRESH) || rowmap[id] < 0)
        topk_insert<T>(cv[base + i], id, lv, li);
    }
  }
  #pragma unroll
  for (int i = 0; i < T; ++i) { sv[t*T+i] = lv[i]; si[t*T+i] = li[i]; }
  __syncthreads();
  if (t < 64) merge4<T>(sv, si, t, sv2, si2);
  __syncthreads();
  if (t < 16) merge4<T>(sv2, si2, t, sv, si);
  __syncthreads();
  if (t < 4)  merge4<T>(sv, si, t, sv2, si2);
  __syncthreads();
  if (t == 0) {
    float fv[T]; int fi[T];
    #pragma unroll
    for (int i = 0; i < T; ++i) { fv[i] = -FLT_MAX; fi[i] = 0x7fffffff; }
    for (int c = 0; c < 4*T; ++c) topk_insert<T>(sv2[c], si2[c], fv, fi);
    #pragma unroll
    for (int i = 0; i < T; ++i) topout[q*6 + i] = fi[i] & ~FRESH;
  }
}

// ---------------- losses ---------------------------------------------------
__global__ __launch_bounds__(384) void loss_softmax_kernel(
    const int* __restrict__ topfeat, const int* __restrict__ rowmap,
    const float* __restrict__ fc1m, const float* __restrict__ fc1U,
    const float* __restrict__ fc2m, const float* __restrict__ fc2U,
    float* __restrict__ out)
{
  __shared__ float sbuf[8];
  int p = blockIdx.x;                // 0..319
  int q = p / 5, j = p % 5 + 1;
  int row = topfeat[q*6 + j];
  int u = rowmap[row];
  const float* r1 = (u >= 0) ? (fc1U + (size_t)u * CC) : (fc1m + (size_t)row * CC);
  const float* r2 = (u >= 0) ? (fc2U + (size_t)u * CC) : (fc2m + (size_t)row * CC);
  int t = threadIdx.x;
  float v = (t < CC) ? fabsf(r1[t] - r2[t]) : 0.f;
  float s = blockReduceSum(v, sbuf);
  if (t == 0) atomicAdd(out, s * (1.f / (320.f * 345.f)));
}

__global__ __launch_bounds__(256) void loss_feature_kernel(
    const int* __restrict__ topfc1, const int* __restrict__ topfc2,
    const int* __restrict__ rowmap, const float* __restrict__ featm,
    const float* __restrict__ featU, float* __restrict__ out)
{
  __shared__ float sbuf[8];
  int p = blockIdx.x;                // 0..255
  int q = p / 4, j = p % 4 + 1;
  int ra = topfc1[q*6 + j], rb = topfc2[q*6 + j];
  int ua = rowmap[ra], ub = rowmap[rb];
  const float* A  = (ua >= 0) ? (featU + (size_t)ua * DF) : (featm + (size_t)ra * DF);
  const float* Bp = (ub >= 0) ? (featU + (size_t)ub * DF) : (featm + (size_t)rb * DF);
  int t = threadIdx.x;               // 256 == DF
  float a = A[t], b = Bp[t];
  float saa = blockReduceSum(a*a, sbuf);
  float sbb = blockReduceSum(b*b, sbuf);
  float sab = blockReduceSum(a*b, sbuf);
  if (t == 0) {
    float fd = 0.5f * (1.f - sab / (fmaxf(sqrtf(saa), EPSN) * fmaxf(sqrtf(sbb), EPSN)));
    atomicAdd(out + 1, fd * (1.f / 256.f));
  }
}

// ---------------- launch ---------------------------------------------------
extern "C" void kernel_launch(void* const* d_in, const int* in_sizes, int n_in,
                              void* d_out, int out_size, void* d_ws, size_t ws_size,
                              hipStream_t stream)
{
  const float* tf    = (const float*)d_in[0];
  const float* fc1   = (const float*)d_in[1];
  const float* fc2   = (const float*)d_in[2];
  const int*   idx   = (const int*)d_in[3];
  const float* featm = (const float*)d_in[4];
  const float* fc1m  = (const float*)d_in[5];
  const float* fc2m  = (const float*)d_in[6];
  float* out = (float*)d_out;

  const int N     = in_sizes[4] / DF;    // 200000
  const int TILES = N / 16;              // 12500
  const int NTQ   = TILES / NBM;         // 16
  const int NTR   = TILES - NTQ * NBM;   // 212
  const int NBLKS = NBM + 4;             // + 4 updated-row blocks
  const int NSLOT = NBLKS * 4;           // 4 row-partition slots per block

  char* w = (char*)d_ws;
  auto alloc = [&](size_t bytes) {
    char* p = w;
    w += (bytes + 255) & ~(size_t)255;
    return (void*)p;
  };
  short* Qp_feat = (short*)alloc((size_t)4 * KSF * 64 * 8 * 2);
  short* Qp_fc1  = (short*)alloc((size_t)4 * KSC * 64 * 8 * 2);
  short* Qp_fc2  = (short*)alloc((size_t)4 * KSC * 64 * 8 * 2);
  float* featU   = (float*)alloc((size_t)NQ * DF * 4);
  float* fc1U    = (float*)alloc((size_t)NQ * CC * 4);
  float* fc2U    = (float*)alloc((size_t)NQ * CC * 4);
  int*   rowmap  = (int*)alloc((size_t)N * 4);
  int*   topfeat = (int*)alloc(NQ * 6 * 4);
  int*   topfc1  = (int*)alloc(NQ * 6 * 4);
  int*   topfc2  = (int*)alloc(NQ * 6 * 4);
  float* cand_v  = (float*)alloc((size_t)NSLOT * 64 * 6 * 4);
  int*   cand_i  = (int*)alloc((size_t)NSLOT * 64 * 6 * 4);

  zero_out<<<1, 64, 0, stream>>>(out);
  fill_rowmap<<<(N + 255) / 256, 256, 0, stream>>>(rowmap, N);
  prep_kernel<<<NQ, 384, 0, stream>>>(tf, fc1, fc2, idx, featm, fc1m, fc2m,
      Qp_feat, Qp_fc1, Qp_fc2, featU, fc1U, fc2U, rowmap);

  // feature: top-6 (drop first, keep 5)
  dist_topk11<DF, KSF, 6><<<NBLKS, 256, 0, stream>>>(
      featm, featU, idx, (const short8*)Qp_feat, cand_v, cand_i, NBM, NTQ, NTR);
  merge_fused<6><<<NQ, 256, 0, stream>>>(cand_v, cand_i, rowmap, NSLOT, topfeat);

  // fc1: top-5 (drop first, keep 4)
  dist_topk11<CC, KSC, 5><<<NBLKS, 256, 0, stream>>>(
      fc1m, fc1U, idx, (const short8*)Qp_fc1, cand_v, cand_i, NBM, NTQ, NTR);
  merge_fused<5><<<NQ, 256, 0, stream>>>(cand_v, cand_i, rowmap, NSLOT, topfc1);

  // fc2: top-5
  dist_topk11<CC, KSC, 5><<<NBLKS, 256, 0, stream>>>(
      fc2m, fc2U, idx, (const short8*)Qp_fc2, cand_v, cand_i, NBM, NTQ, NTR);
  merge_fused<5><<<NQ, 256, 0, stream>>>(cand_v, cand_i, rowmap, NSLOT, topfc2);

  loss_softmax_kernel<<<320, 384, 0, stream>>>(topfeat, rowmap, fc1m, fc1U, fc2m, fc2U, out);
  loss_feature_kernel<<<256, 256, 0, stream>>>(topfc1, topfc2, rowmap, featm, featU, out);
}

// Round 20
// 646.853 us; speedup vs baseline: 1.1642x; 1.1642x over previous
//
#include <hip/hip_runtime.h>
#include <hip/hip_bf16.h>
#include <float.h>
#include <math.h>

#define NQ    64
#define DF    256
#define CC    345
#define KSF   8      // 256/32
#define KSC   11     // ceil(345/32)
#define NBM   768    // main dist blocks
#define BMW   6250   // bitmask words for N=200000
#define FRESH (1 << 30)
#define EPSN  1e-12f

typedef __attribute__((ext_vector_type(8))) short short8;
typedef __attribute__((ext_vector_type(4))) float f32x4;

// ---- global->LDS DMA (size is a literal) ---------------------------------
__device__ __forceinline__ void gld16(const void* g, void* l) {
  __builtin_amdgcn_global_load_lds(
      static_cast<const uint32_t*>(g), static_cast<uint32_t*>(l), 16, 0, 0);
}
__device__ __forceinline__ void gld4(const void* g, void* l) {
  __builtin_amdgcn_global_load_lds(
      static_cast<const uint32_t*>(g), static_cast<uint32_t*>(l), 4, 0, 0);
}

// ---- counted waitcnt helpers (literal N; sched fence per rule #18) -------
__device__ __forceinline__ void wait_vm0() {
  asm volatile("s_waitcnt vmcnt(0)" ::: "memory");
  __builtin_amdgcn_sched_barrier(0);
}
__device__ __forceinline__ void wait_vm4() {
  asm volatile("s_waitcnt vmcnt(4)" ::: "memory");
  __builtin_amdgcn_sched_barrier(0);
}
__device__ __forceinline__ void wait_vm8() {
  asm volatile("s_waitcnt vmcnt(8)" ::: "memory");
  __builtin_amdgcn_sched_barrier(0);
}
__device__ __forceinline__ void wait_vm9() {
  asm volatile("s_waitcnt vmcnt(9)" ::: "memory");
  __builtin_amdgcn_sched_barrier(0);
}
__device__ __forceinline__ void wait_lgkm0() {
  asm volatile("s_waitcnt lgkmcnt(0)" ::: "memory");
  __builtin_amdgcn_sched_barrier(0);
}
__device__ __forceinline__ void raw_barrier() {
  __builtin_amdgcn_sched_barrier(0);
  __builtin_amdgcn_s_barrier();
  __builtin_amdgcn_sched_barrier(0);
}

// ---------------- zero d_out ----------------------------------------------
__global__ void zero_out(float* out) {
  if (threadIdx.x < 2) out[threadIdx.x] = 0.f;
}

// ---------------- block-wide reductions -----------------------------------
__device__ __forceinline__ float blockReduceSum(float v, float* sbuf) {
  __syncthreads();
  #pragma unroll
  for (int o = 32; o > 0; o >>= 1) v += __shfl_down(v, o);
  int w = threadIdx.x >> 6;
  if ((threadIdx.x & 63) == 0) sbuf[w] = v;
  __syncthreads();
  if (threadIdx.x == 0) {
    float s = 0.f;
    int nw = blockDim.x >> 6;
    for (int i = 0; i < nw; ++i) s += sbuf[i];
    sbuf[0] = s;
  }
  __syncthreads();
  return sbuf[0];
}

__device__ __forceinline__ float blockReduceMax(float v, float* sbuf) {
  __syncthreads();
  #pragma unroll
  for (int o = 32; o > 0; o >>= 1) v = fmaxf(v, __shfl_down(v, o));
  int w = threadIdx.x >> 6;
  if ((threadIdx.x & 63) == 0) sbuf[w] = v;
  __syncthreads();
  if (threadIdx.x == 0) {
    float s = -FLT_MAX;
    int nw = blockDim.x >> 6;
    for (int i = 0; i < nw; ++i) s = fmaxf(s, sbuf[i]);
    sbuf[0] = s;
  }
  __syncthreads();
  return sbuf[0];
}

// ------------- top-k insert, list sorted (value desc, index asc) ----------
template<int T>
__device__ __forceinline__ void topk_insert(float v, int id, float (&lv)[T], int (&li)[T]) {
  if (!((v > lv[T-1]) || (v == lv[T-1] && id < li[T-1]))) return;
  #pragma unroll
  for (int p = T-1; p > 0; --p) {
    bool up = (v > lv[p-1]) || (v == lv[p-1] && id < li[p-1]);
    if (up) { lv[p] = lv[p-1]; li[p] = li[p-1]; }
    else    { lv[p] = v; li[p] = id; return; }
  }
  lv[0] = v; li[0] = id;
}

template<int T>
__device__ __forceinline__ void merge4(const float* sv, const int* si, int t,
                                       float* dv, int* di) {
  float fv[T]; int fi[T];
  #pragma unroll
  for (int i = 0; i < T; ++i) { fv[i] = -FLT_MAX; fi[i] = 0x7fffffff; }
  for (int s = 0; s < 4; ++s)
    #pragma unroll
    for (int i = 0; i < T; ++i)
      topk_insert<T>(sv[(t*4+s)*T+i], si[(t*4+s)*T+i], fv, fi);
  #pragma unroll
  for (int i = 0; i < T; ++i) { dv[t*T+i] = fv[i]; di[t*T+i] = fi[i]; }
}

// ---------------- rowmap fill ---------------------------------------------
__global__ void fill_rowmap(int* rowmap, int n) {
  int i = blockIdx.x * blockDim.x + threadIdx.x;
  if (i < n) rowmap[i] = -1;
}

// -------- prep: softmax, normalize queries -> MFMA frag pack, updates -----
__global__ __launch_bounds__(384) void prep_kernel(
    const float* __restrict__ tf, const float* __restrict__ fc1,
    const float* __restrict__ fc2, const int* __restrict__ idx,
    const float* __restrict__ featm, const float* __restrict__ fc1m,
    const float* __restrict__ fc2m,
    short* __restrict__ Qp_feat, short* __restrict__ Qp_fc1, short* __restrict__ Qp_fc2,
    float* __restrict__ featU, float* __restrict__ fc1U, float* __restrict__ fc2U,
    int* __restrict__ rowmap)
{
  __shared__ float sbuf[8];
  const int b = blockIdx.x, t = threadIdx.x;
  const int trow = idx[b];
  const int qt = b >> 4, qr = b & 15;

  {
    float x = (t < DF) ? tf[b*DF + t] : 0.f;
    float ss = blockReduceSum(x*x, sbuf);
    float inv = 1.f / fmaxf(sqrtf(ss), EPSN);
    if (t < DF) {
      featU[b*DF + t] = 0.9f * featm[(size_t)trow*DF + t] + 0.1f * x;
      int ks = t >> 5, lg = (t >> 3) & 3, j = t & 7;
      int lane = qr + lg*16;
      union { __hip_bfloat16 h; short s; } cv;
      cv.h = __float2bfloat16(x * inv);
      Qp_feat[((qt*KSF + ks)*64 + lane)*8 + j] = cv.s;
    }
  }
  {
    float y = (t < CC) ? fc1[b*CC + t] : -FLT_MAX;
    float mx = blockReduceMax(y, sbuf);
    float e = (t < CC) ? expf(y - mx) : 0.f;
    float se = blockReduceSum(e, sbuf);
    float s = e / se;
    float s2 = blockReduceSum(s*s, sbuf);
    float inv2 = 1.f / fmaxf(sqrtf(s2), EPSN);
    if (t < CC) fc1U[b*CC + t] = 0.9f * fc1m[(size_t)trow*CC + t] + 0.1f * s;
    if (t < KSC*32) {
      int ks = t >> 5, lg = (t >> 3) & 3, j = t & 7;
      int lane = qr + lg*16;
      union { __hip_bfloat16 h; short s; } cv;
      cv.h = __float2bfloat16((t < CC) ? s * inv2 : 0.f);
      Qp_fc1[((qt*KSC + ks)*64 + lane)*8 + j] = cv.s;
    }
  }
  {
    float y = (t < CC) ? fc2[b*CC + t] : -FLT_MAX;
    float mx = blockReduceMax(y, sbuf);
    float e = (t < CC) ? expf(y - mx) : 0.f;
    float se = blockReduceSum(e, sbuf);
    float s = e / se;
    float s2 = blockReduceSum(s*s, sbuf);
    float inv2 = 1.f / fmaxf(sqrtf(s2), EPSN);
    if (t < CC) fc2U[b*CC + t] = 0.9f * fc2m[(size_t)trow*CC + t] + 0.1f * s;
    if (t < KSC*32) {
      int ks = t >> 5, lg = (t >> 3) & 3, j = t & 7;
      int lane = qr + lg*16;
      union { __hip_bfloat16 h; short s; } cv;
      cv.h = __float2bfloat16((t < CC) ? s * inv2 : 0.f);
      Qp_fc2[((qt*KSC + ks)*64 + lane)*8 + j] = cv.s;
    }
  }
  if (t == 0) rowmap[trow] = b;
}

// -------- dist (r14 verbatim except cand layout [q][slot][T]) -------------
template<int D, int KS, int T>
__global__ __launch_bounds__(256, 3) void dist_topk11(
    const float* __restrict__ bank, const float* __restrict__ ubank,
    const int* __restrict__ uids, const short8* __restrict__ Qp,
    float* __restrict__ cand_v, int* __restrict__ cand_i,
    int nmain, int ntq, int ntr, int nslot)
{
  constexpr bool FEAT = (D == 256);
  constexpr int GROW = D * 4;                  // global row bytes: 1024/1380
  constexpr int SROW = FEAT ? 1024 : 1392;     // LDS row stride (16B mult)
  constexpr int BUFB = 16 * SROW;

  __shared__ __align__(16) char smem[2*BUFB + 128];
  char* k344 = smem + 2*BUFB;                  // [2][16] f32 (fc k=344)

  const int t = threadIdx.x, l = t & 63, w = t >> 6;
  const int lc = l & 15, lg = l >> 4;
  const bool corr = ((int)blockIdx.x >= nmain);
  const float* srcb = corr ? ubank : bank;

  int tile0, nt;
  if (corr) { tile0 = blockIdx.x - nmain; nt = 1; }
  else {
    int b = blockIdx.x;
    tile0 = b*ntq + (b < ntr ? b : ntr);
    nt = ntq + (b < ntr ? 1 : 0);
  }

  short8 afr[KS];                              // wave w's 16 queries (B-op)
  #pragma unroll
  for (int ks = 0; ks < KS; ++ks) afr[ks] = Qp[(w*KS + ks)*64 + l];

  auto STAGE = [&](int tile, int pn) {
    const char* tb = (const char*)srcb + (size_t)tile * (size_t)(16*GROW);
    char* bb = smem + pn*BUFB;
    #pragma unroll
    for (int r2 = 0; r2 < 4; ++r2) {
      int row = w*4 + r2;                      // wave-uniform
      if (FEAT) {
        // pre-swizzled source so swizzled reads see linear data (rule #21)
        gld16(tb + row*1024 + ((l ^ (row & 7)) * 16), bb + row*1024);
      } else {
        gld16(tb + row*1380 + l*16, bb + row*1392);
        if (l < 22) gld16(tb + row*1380 + 1024 + l*16, bb + row*1392 + 1024);
      }
    }
    if (!FEAT && w == 0 && l < 16)
      gld4(tb + l*1380 + 1376, k344 + pn*64);
  };

  STAGE(tile0, 0);
  if (nt > 1) STAGE(tile0 + 1, 1);

  float lv[T]; int li[T];
  #pragma unroll
  for (int i = 0; i < T; ++i) { lv[i] = -FLT_MAX; li[i] = 0x7fffffff; }

  for (int it = 0; it < nt; ++it) {
    const int pn = it & 1;

    // wait: tile it's stage complete; tile it+1 stays in flight
    if (it + 1 < nt) {
      if (FEAT) wait_vm4();
      else if (w == 0) wait_vm9();
      else wait_vm8();
    } else {
      wait_vm0();
    }
    raw_barrier();                             // all waves' portions landed

    const char* bb = smem + pn*BUFB;
    f32x4 acc = (f32x4){0.f, 0.f, 0.f, 0.f};
    float sq = 0.f;

    #pragma unroll
    for (int ks = 0; ks < KS; ++ks) {
      float v[8];
      if (!FEAT && ks == KS-1 && lg == 3) {    // fc tail: only k=344 valid
        v[0] = *(const float*)(k344 + pn*64 + lc*4);
        #pragma unroll
        for (int j = 1; j < 8; ++j) v[j] = 0.f;
      } else if (FEAT) {
        int g0 = ks*8 + lg*2;
        float4 a = *(const float4*)(bb + lc*1024 + ((g0 ^ (lc & 7)) * 16));
        float4 c = *(const float4*)(bb + lc*1024 + (((g0 + 1) ^ (lc & 7)) * 16));
        v[0]=a.x; v[1]=a.y; v[2]=a.z; v[3]=a.w;
        v[4]=c.x; v[5]=c.y; v[6]=c.z; v[7]=c.w;
      } else {
        const char* p = bb + lc*1392 + ks*128 + lg*32;
        float4 a = *(const float4*)p;
        float4 c = *(const float4*)(p + 16);
        v[0]=a.x; v[1]=a.y; v[2]=a.z; v[3]=a.w;
        v[4]=c.x; v[5]=c.y; v[6]=c.z; v[7]=c.w;
      }
      #pragma unroll
      for (int j = 0; j < 8; ++j) sq += v[j]*v[j];
      union { short8 s8; __hip_bfloat162 h2[4]; } fb;
      #pragma unroll
      for (int j = 0; j < 4; ++j)
        fb.h2[j] = __float22bfloat162_rn(make_float2(v[2*j], v[2*j+1]));
      // SWAPPED: rows as A, queries as B -> D[row][query]
      acc = __builtin_amdgcn_mfma_f32_16x16x32_bf16(fb.s8, afr[ks], acc, 0, 0, 0);
    }

    // row norms: lane holds row lc's partial; xor-reduce; redistribute
    float s = sq;
    s += __shfl_xor(s, 16);
    s += __shfl_xor(s, 32);
    float ri_own = 1.f / fmaxf(sqrtf(s), EPSN);   // norm of row lc
    float ri[4];
    #pragma unroll
    for (int j = 0; j < 4; ++j) ri[j] = __shfl(ri_own, lg*4 + j);

    wait_lgkm0();                              // all LDS reads of buf pn done
    raw_barrier();
    if (it + 2 < nt) STAGE(tile0 + it + 2, pn);  // refill freed buffer

    // register-only topk: lane (lc,lg) = query w*16+lc, rows lg*4+{0..3}
    if (corr) {
      #pragma unroll
      for (int j = 0; j < 4; ++j)
        topk_insert<T>(acc[j] * ri[j], uids[tile0*16 + lg*4 + j] | FRESH, lv, li);
    } else {
      const int gb = (tile0 + it) * 16 + lg*4;
      #pragma unroll
      for (int j = 0; j < 4; ++j)
        topk_insert<T>(acc[j] * ri[j], gb + j, lv, li);
    }
  }

  // write out: [query][slot][T]; slot = blockIdx*4 + lg, q = w*16 + lc
  size_t base = (((size_t)(w*16 + lc))*nslot + (size_t)blockIdx.x*4 + lg)*T;
  #pragma unroll
  for (int i = 0; i < T; ++i) { cand_v[base + i] = lv[i]; cand_i[base + i] = li[i]; }
}

// -------- merge stage 1: 8 blocks/query, coalesced reads, LDS bitmask -----
template<int T>
__global__ __launch_bounds__(256) void merge_stage1(
    const float* __restrict__ cv, const int* __restrict__ ci,
    const int* __restrict__ uids, int nslots,
    float* __restrict__ midv, int* __restrict__ midi)
{
  __shared__ unsigned bm[BMW];
  __shared__ float sv[256*T]; __shared__ int si[256*T];
  __shared__ float sv2[64*T]; __shared__ int si2[64*T];
  const int q = blockIdx.x >> 3, s = blockIdx.x & 7, t = threadIdx.x;
  // updated-row bitmask (stale filter without HBM gather)
  for (int i = t; i < BMW; i += 256) bm[i] = 0u;
  __syncthreads();
  if (t < 64) { int r = uids[t]; atomicOr(&bm[r >> 5], 1u << (r & 31)); }
  __syncthreads();

  const int len = (nslots + 7) >> 3;
  const int lo = s*len, hi = min(nslots, lo + len);
  float lv[T]; int li[T];
  #pragma unroll
  for (int i = 0; i < T; ++i) { lv[i] = -FLT_MAX; li[i] = 0x7fffffff; }
  for (int c = lo + t; c < hi; c += 256) {
    size_t base = ((size_t)q*nslots + c)*T;     // contiguous per block
    #pragma unroll
    for (int i = 0; i < T; ++i) {
      int id = ci[base + i];
      int rid = id & ~FRESH;
      bool fresh = (id & FRESH) != 0;
      bool stale = !fresh && ((bm[rid >> 5] >> (rid & 31)) & 1u);
      if (!stale)
        topk_insert<T>(cv[base + i], id, lv, li);
    }
  }
  #pragma unroll
  for (int i = 0; i < T; ++i) { sv[t*T+i] = lv[i]; si[t*T+i] = li[i]; }
  __syncthreads();
  if (t < 64) merge4<T>(sv, si, t, sv2, si2);
  __syncthreads();
  if (t < 16) merge4<T>(sv2, si2, t, sv, si);
  __syncthreads();
  if (t < 4)  merge4<T>(sv, si, t, sv2, si2);
  __syncthreads();
  if (t == 0) {
    float fv[T]; int fi[T];
    #pragma unroll
    for (int i = 0; i < T; ++i) { fv[i] = -FLT_MAX; fi[i] = 0x7fffffff; }
    for (int c = 0; c < 4*T; ++c) topk_insert<T>(sv2[c], si2[c], fv, fi);
    #pragma unroll
    for (int i = 0; i < T; ++i) {
      midv[blockIdx.x*T + i] = fv[i];
      midi[blockIdx.x*T + i] = fi[i];
    }
  }
}

// -------- merge stage 2: final top-T per query (strip FRESH flag) ---------
template<int T>
__global__ __launch_bounds__(64) void merge_stage2(
    const float* __restrict__ midv, const int* __restrict__ midi,
    int* __restrict__ topout)      // stride 6
{
  __shared__ float sv[8*T]; __shared__ int si[8*T];
  const int q = blockIdx.x, t = threadIdx.x;
  if (t < 8*T) { sv[t] = midv[q*8*T + t]; si[t] = midi[q*8*T + t]; }
  __syncthreads();
  if (t == 0) {
    float fv[T]; int fi[T];
    #pragma unroll
    for (int i = 0; i < T; ++i) { fv[i] = -FLT_MAX; fi[i] = 0x7fffffff; }
    for (int c = 0; c < 8*T; ++c) topk_insert<T>(sv[c], si[c], fv, fi);
    #pragma unroll
    for (int i = 0; i < T; ++i) topout[q*6 + i] = fi[i] & ~FRESH;
  }
}

// ---------------- losses ---------------------------------------------------
__global__ __launch_bounds__(384) void loss_softmax_kernel(
    const int* __restrict__ topfeat, const int* __restrict__ rowmap,
    const float* __restrict__ fc1m, const float* __restrict__ fc1U,
    const float* __restrict__ fc2m, const float* __restrict__ fc2U,
    float* __restrict__ out)
{
  __shared__ float sbuf[8];
  int p = blockIdx.x;                // 0..319
  int q = p / 5, j = p % 5 + 1;
  int row = topfeat[q*6 + j];
  int u = rowmap[row];
  const float* r1 = (u >= 0) ? (fc1U + (size_t)u * CC) : (fc1m + (size_t)row * CC);
  const float* r2 = (u >= 0) ? (fc2U + (size_t)u * CC) : (fc2m + (size_t)row * CC);
  int t = threadIdx.x;
  float v = (t < CC) ? fabsf(r1[t] - r2[t]) : 0.f;
  float s = blockReduceSum(v, sbuf);
  if (t == 0) atomicAdd(out, s * (1.f / (320.f * 345.f)));
}

__global__ __launch_bounds__(256) void loss_feature_kernel(
    const int* __restrict__ topfc1, const int* __restrict__ topfc2,
    const int* __restrict__ rowmap, const float* __restrict__ featm,
    const float* __restrict__ featU, float* __restrict__ out)
{
  __shared__ float sbuf[8];
  int p = blockIdx.x;                // 0..255
  int q = p / 4, j = p % 4 + 1;
  int ra = topfc1[q*6 + j], rb = topfc2[q*6 + j];
  int ua = rowmap[ra], ub = rowmap[rb];
  const float* A  = (ua >= 0) ? (featU + (size_t)ua * DF) : (featm + (size_t)ra * DF);
  const float* Bp = (ub >= 0) ? (featU + (size_t)ub * DF) : (featm + (size_t)rb * DF);
  int t = threadIdx.x;               // 256 == DF
  float a = A[t], b = Bp[t];
  float saa = blockReduceSum(a*a, sbuf);
  float sbb = blockReduceSum(b*b, sbuf);
  float sab = blockReduceSum(a*b, sbuf);
  if (t == 0) {
    float fd = 0.5f * (1.f - sab / (fmaxf(sqrtf(saa), EPSN) * fmaxf(sqrtf(sbb), EPSN)));
    atomicAdd(out + 1, fd * (1.f / 256.f));
  }
}

// ---------------- launch ---------------------------------------------------
extern "C" void kernel_launch(void* const* d_in, const int* in_sizes, int n_in,
                              void* d_out, int out_size, void* d_ws, size_t ws_size,
                              hipStream_t stream)
{
  const float* tf    = (const float*)d_in[0];
  const float* fc1   = (const float*)d_in[1];
  const float* fc2   = (const float*)d_in[2];
  const int*   idx   = (const int*)d_in[3];
  const float* featm = (const float*)d_in[4];
  const float* fc1m  = (const float*)d_in[5];
  const float* fc2m  = (const float*)d_in[6];
  float* out = (float*)d_out;

  const int N     = in_sizes[4] / DF;    // 200000
  const int TILES = N / 16;              // 12500
  const int NTQ   = TILES / NBM;         // 16
  const int NTR   = TILES - NTQ * NBM;   // 212
  const int NBLKS = NBM + 4;             // + 4 updated-row blocks
  const int NSLOT = NBLKS * 4;           // 4 row-partition slots per block

  char* w = (char*)d_ws;
  auto alloc = [&](size_t bytes) {
    char* p = w;
    w += (bytes + 255) & ~(size_t)255;
    return (void*)p;
  };
  short* Qp_feat = (short*)alloc((size_t)4 * KSF * 64 * 8 * 2);
  short* Qp_fc1  = (short*)alloc((size_t)4 * KSC * 64 * 8 * 2);
  short* Qp_fc2  = (short*)alloc((size_t)4 * KSC * 64 * 8 * 2);
  float* featU   = (float*)alloc((size_t)NQ * DF * 4);
  float* fc1U    = (float*)alloc((size_t)NQ * CC * 4);
  float* fc2U    = (float*)alloc((size_t)NQ * CC * 4);
  int*   rowmap  = (int*)alloc((size_t)N * 4);
  int*   topfeat = (int*)alloc(NQ * 6 * 4);
  int*   topfc1  = (int*)alloc(NQ * 6 * 4);
  int*   topfc2  = (int*)alloc(NQ * 6 * 4);
  float* cand_v  = (float*)alloc((size_t)NQ * NSLOT * 6 * 4);
  int*   cand_i  = (int*)alloc((size_t)NQ * NSLOT * 6 * 4);
  float* midv    = (float*)alloc((size_t)NQ * 8 * 6 * 4);
  int*   midi    = (int*)alloc((size_t)NQ * 8 * 6 * 4);

  zero_out<<<1, 64, 0, stream>>>(out);
  fill_rowmap<<<(N + 255) / 256, 256, 0, stream>>>(rowmap, N);
  prep_kernel<<<NQ, 384, 0, stream>>>(tf, fc1, fc2, idx, featm, fc1m, fc2m,
      Qp_feat, Qp_fc1, Qp_fc2, featU, fc1U, fc2U, rowmap);

  // feature: top-6 (drop first, keep 5)
  dist_topk11<DF, KSF, 6><<<NBLKS, 256, 0, stream>>>(
      featm, featU, idx, (const short8*)Qp_feat, cand_v, cand_i, NBM, NTQ, NTR, NSLOT);
  merge_stage1<6><<<NQ*8, 256, 0, stream>>>(cand_v, cand_i, idx, NSLOT, midv, midi);
  merge_stage2<6><<<NQ, 64, 0, stream>>>(midv, midi, topfeat);

  // fc1: top-5 (drop first, keep 4)
  dist_topk11<CC, KSC, 5><<<NBLKS, 256, 0, stream>>>(
      fc1m, fc1U, idx, (const short8*)Qp_fc1, cand_v, cand_i, NBM, NTQ, NTR, NSLOT);
  merge_stage1<5><<<NQ*8, 256, 0, stream>>>(cand_v, cand_i, idx, NSLOT, midv, midi);
  merge_stage2<5><<<NQ, 64, 0, stream>>>(midv, midi, topfc1);

  // fc2: top-5
  dist_topk11<CC, KSC, 5><<<NBLKS, 256, 0, stream>>>(
      fc2m, fc2U, idx, (const short8*)Qp_fc2, cand_v, cand_i, NBM, NTQ, NTR, NSLOT);
  merge_stage1<5><<<NQ*8, 256, 0, stream>>>(cand_v, cand_i, idx, NSLOT, midv, midi);
  merge_stage2<5><<<NQ, 64, 0, stream>>>(midv, midi, topfc2);

  loss_softmax_kernel<<<320, 384, 0, stream>>>(topfeat, rowmap, fc1m, fc1U, fc2m, fc2U, out);
  loss_feature_kernel<<<256, 256, 0, stream>>>(topfc1, topfc2, rowmap, featm, featU, out);
}